// Round 10
// baseline (1388.363 us; speedup 1.0000x reference)
//
#include <hip/hip_runtime.h>
#include <cstdint>
#include <cstddef>

#define B_   4
#define S_   2048
#define D_   2048
#define NH_  16
#define NKV_ 4
#define HD_  128

typedef __attribute__((ext_vector_type(8))) short short8;
typedef __attribute__((ext_vector_type(4))) float f32x4;

// ---------------------------------------------------------------------------
// fp32 -> (bf16_hi, bf16_lo) split helpers (RNE)
// ---------------------------------------------------------------------------
__device__ __forceinline__ unsigned short f2bf(float f) {
    union { float f; unsigned u; } v{f};
    unsigned r = v.u + 0x7FFF + ((v.u >> 16) & 1);
    return (unsigned short)(r >> 16);
}
__device__ __forceinline__ float bf2f(unsigned short h) {
    union { unsigned u; float f; } v{(unsigned)h << 16};
    return v.f;
}
__device__ __forceinline__ void split1(float f, unsigned short& h, unsigned short& l) {
    h = f2bf(f);
    l = f2bf(f - bf2f(h));
}
// 8 packed u32 (hi|lo<<16) -> two bf16x8 fragments
__device__ __forceinline__ void unpack8(const unsigned* w, short8& hi, short8& lo) {
    unsigned h[4], l[4];
#pragma unroll
    for (int i = 0; i < 4; ++i) {
        h[i] = (w[2*i] & 0xFFFFu) | (w[2*i+1] << 16);
        l[i] = (w[2*i] >> 16) | (w[2*i+1] & 0xFFFF0000u);
    }
    hi = *(short8*)h; lo = *(short8*)l;
}

// src fp32 [n] -> hi/lo bf16 [n]. n must be a multiple of 1024.
__global__ __launch_bounds__(256) void split_bf16_k(
    const float* __restrict__ src, ushort* __restrict__ hi, ushort* __restrict__ lo)
{
    size_t i = ((size_t)blockIdx.x * 256 + threadIdx.x) * 4;
    float4 f = *(const float4*)&src[i];
    ushort4 h, l;
    split1(f.x, h.x, l.x); split1(f.y, h.y, l.y);
    split1(f.z, h.z, l.z); split1(f.w, h.w, l.w);
    *(ushort4*)&hi[i] = h;
    *(ushort4*)&lo[i] = l;
}

// ---------------------------------------------------------------------------
// Split-bf16 MFMA GEMM (round-3 verified form):
// C[M,N] = (Ah+Al)[M,K] @ (Bh+Bl)[N,K]^T + bias  (drops lo*lo)
// ---------------------------------------------------------------------------
__global__ __launch_bounds__(256) void gemm_mfma_split(
    const ushort* __restrict__ Ah, const ushort* __restrict__ Al,
    const ushort* __restrict__ Bh, const ushort* __restrict__ Bl,
    const float* __restrict__ bias, float* __restrict__ C,
    int M, int N, int K)
{
    __shared__ ushort sA[2][128 * 32];   // [0]=hi [1]=lo, row-major [128][32]
    __shared__ ushort sB[2][128 * 32];

    const int tid  = threadIdx.x;
    const int wave = tid >> 6;
    const int lane = tid & 63;
    const int bm = blockIdx.y * 128;
    const int bn = blockIdx.x * 128;
    const int wm = (wave & 1) * 64;
    const int wn = (wave >> 1) * 64;

    f32x4 acc[4][4];
#pragma unroll
    for (int mt = 0; mt < 4; ++mt)
#pragma unroll
        for (int nt = 0; nt < 4; ++nt) acc[mt][nt] = 0.f;

    const ushort* gbase = (wave == 0) ? Ah : (wave == 1) ? Al : (wave == 2) ? Bh : Bl;
    ushort* sbase = (wave == 0) ? sA[0] : (wave == 1) ? sA[1] : (wave == 2) ? sB[0] : sB[1];
    const int rb   = (wave < 2) ? bm : bn;
    const int lrow = lane >> 2;          // 0..15
    const int lcol = (lane & 3) * 8;     // element offset in k

    const int koff = (lane >> 4) * 8;
    const int rsel = lane & 15;

    for (int k0 = 0; k0 < K; k0 += 32) {
        __syncthreads();
        const ushort* g0 = gbase + (size_t)(rb + lrow) * K + k0 + lcol;
#pragma unroll
        for (int i = 0; i < 8; ++i) {
            __builtin_amdgcn_global_load_lds(
                (const __attribute__((address_space(1))) unsigned int*)(g0 + (size_t)i * 16 * K),
                (__attribute__((address_space(3))) unsigned int*)(sbase + i * 512),
                16, 0, 0);
        }
        __syncthreads();

        short8 a_h[4], a_l[4], b_h[4], b_l[4];
#pragma unroll
        for (int t = 0; t < 4; ++t) {
            a_h[t] = *(const short8*)&sA[0][(wm + t * 16 + rsel) * 32 + koff];
            a_l[t] = *(const short8*)&sA[1][(wm + t * 16 + rsel) * 32 + koff];
            b_h[t] = *(const short8*)&sB[0][(wn + t * 16 + rsel) * 32 + koff];
            b_l[t] = *(const short8*)&sB[1][(wn + t * 16 + rsel) * 32 + koff];
        }
#pragma unroll
        for (int mt = 0; mt < 4; ++mt)
#pragma unroll
            for (int nt = 0; nt < 4; ++nt) {
                acc[mt][nt] = __builtin_amdgcn_mfma_f32_16x16x32_bf16(a_h[mt], b_h[nt], acc[mt][nt], 0, 0, 0);
                acc[mt][nt] = __builtin_amdgcn_mfma_f32_16x16x32_bf16(a_h[mt], b_l[nt], acc[mt][nt], 0, 0, 0);
                acc[mt][nt] = __builtin_amdgcn_mfma_f32_16x16x32_bf16(a_l[mt], b_h[nt], acc[mt][nt], 0, 0, 0);
            }
    }

    const int crow0 = bm + wm + (lane >> 4) * 4;
    const int ccol0 = bn + wn + (lane & 15);
#pragma unroll
    for (int nt = 0; nt < 4; ++nt) {
        float bb = bias ? bias[ccol0 + nt * 16] : 0.f;
#pragma unroll
        for (int mt = 0; mt < 4; ++mt)
#pragma unroll
            for (int r = 0; r < 4; ++r)
                C[(size_t)(crow0 + mt * 16 + r) * N + ccol0 + nt * 16] = acc[mt][nt][r] + bb;
    }
}

// ---------------------------------------------------------------------------
// In-place RoPE (+scale) and fp32 -> interleaved hi/lo bf16 split.
// Row r of 128 fp32 becomes 128 hi ushorts | 128 lo ushorts (same 512 bytes).
// ---------------------------------------------------------------------------
__global__ __launch_bounds__(256) void rope_split_kernel(
    float* __restrict__ t, int H, float scale, int do_rope)
{
    const int tid = threadIdx.x;
    const int rid = blockIdx.x * 2 + (tid >> 7);
    const int d   = tid & 127;
    size_t fbase = (size_t)rid * 128;
    float val;
    if (do_rope) {
        const int s = (rid / H) & (S_ - 1);
        const int j = d & 63;
        float inv  = 1.0f / powf(1.0e6f, (float)j * (1.0f / 64.0f));
        float fr = (float)s * inv;
        float sn, cs; sincosf(fr, &sn, &cs);
        float x0 = t[fbase + d];
        float xp = t[fbase + (d ^ 64)];
        float rot = (d < 64) ? -xp : xp;
        val = fmaf(x0, cs, rot * sn) * scale;
    } else {
        val = t[fbase + d] * scale;
    }
    __syncthreads();               // all fp32 reads of these 2 rows done
    unsigned short h, l; split1(val, h, l);
    ushort* us = (ushort*)t;
    us[(size_t)rid * 256 + d]       = h;
    us[(size_t)rid * 256 + 128 + d] = l;
}

// ---------------------------------------------------------------------------
// MFMA causal flash attention, GQA, split-bf16 precision.
// Qsp: interleaved hi/lo Q rows [B,S,NH]x(128h|128l) (read-only here).
// Ksp/Vsp: interleaved hi/lo K/V rows [B,S,NKV]x(128h|128l).
// ctx_h/ctx_l: PLANAR outputs, [B*S][2048] ushorts, feature = h*128+d.
// Block: 4 waves x 32 q-rows per pass (BM=128); KV tile BN=32.
//
// = R7 (complementary q-tile pairing: every block does exactly 68
// tile-units, grid 512 = 2 blocks/CU uniform) + R4's one-barrier
// double-buffered KV pipeline, with R4's spill cause removed:
// __launch_bounds__(256) WITHOUT the min-waves clause. R4 showed (256,2)
// makes the allocator clamp to 128 VGPR (a 4-waves/SIMD boundary) and spill
// (WRITE_SIZE 65->109MB); this kernel needs ~160-200 VGPR for the staging
// registers. Grid is exactly 2 blocks/CU so neither 72.7KB LDS nor higher
// VGPR can cost occupancy.
//
// Per tile: issue K+V global loads for tile t+1 into registers BEFORE
// compute(t) (latency hides under ~600cy of MFMA+softmax), ds_write to the
// alternate LDS buffer AFTER compute, ONE barrier per tile.
//
// KV-row permutation trick: K rows staged at permuted row
// rho(kv) = ((kv&4)<<2) | ((kv>>3)<<2) | (kv&3) so QK^T's C-layout leaves
// each lane holding P at kv = quad*8 + mf*4 + r — exactly the contiguous
// 8-element k-slice its PV A-fragment needs. P never touches LDS.
// ---------------------------------------------------------------------------
__global__ __launch_bounds__(256) void flash_attn_mfma(
    const ushort* __restrict__ Qsp, const ushort* __restrict__ Ksp,
    const ushort* __restrict__ Vsp, ushort* __restrict__ ctx_h,
    ushort* __restrict__ ctx_l)
{
    __shared__ __align__(16) ushort Ks[2][32][280];   // hi at 0, lo at 144 (rows permuted)
    __shared__ __align__(16) unsigned Vt[2][128][36]; // [feat][kv] hi|lo<<16

    const int tid  = threadIdx.x;
    const int wave = tid >> 6;
    const int lane = tid & 63;
    const int l15  = lane & 15;
    const int quad = lane >> 4;
    const int h    = blockIdx.y;
    const int b    = blockIdx.z;
    const int kvh  = h >> 2;

    // staging geometry (constant across tiles/passes)
    const int vrow = tid & 31;          // V: kv row this thread loads
    const int vfs  = tid >> 5;          // V: feature-slice (x16)
    const size_t kvstride = (size_t)NKV_ * 256;
    const ushort* kbase = Ksp + ((size_t)b * S_ * NKV_ + kvh) * 256;
    const ushort* vbase = Vsp + ((size_t)b * S_ * NKV_ + kvh) * 256 + vfs * 16;

    // staging registers (in-flight tile data, live across compute)
    uint4 kstg[4];
    uint4 vstg[4];                      // [0]=hf0 hi [1]=hf0 lo [2]=hf1 hi [3]=hf1 lo

#define LOADKV(K0)                                                              \
    {                                                                           \
        _Pragma("unroll")                                                       \
        for (int i = 0; i < 4; ++i) {                                           \
            int c = tid + i * 256;                                              \
            int row = c >> 5, seg = c & 31;                                     \
            kstg[i] = *(const uint4*)(kbase + (size_t)((K0) + row) * kvstride + seg * 8); \
        }                                                                       \
        const ushort* vs = vbase + (size_t)((K0) + vrow) * kvstride;            \
        vstg[0] = *(const uint4*)(vs);                                          \
        vstg[1] = *(const uint4*)(vs + 128);                                    \
        vstg[2] = *(const uint4*)(vs + 8);                                      \
        vstg[3] = *(const uint4*)(vs + 136);                                    \
    }

#define STOREKV(NB)                                                             \
    {                                                                           \
        _Pragma("unroll")                                                       \
        for (int i = 0; i < 4; ++i) {                                           \
            int c = tid + i * 256;                                              \
            int row = c >> 5, seg = c & 31;                                     \
            int prow = ((row & 4) << 2) | ((row >> 3) << 2) | (row & 3);        \
            *(uint4*)&Ks[NB][prow][seg * 8 + (seg >= 16 ? 16 : 0)] = kstg[i];   \
        }                                                                       \
        _Pragma("unroll")                                                       \
        for (int hf = 0; hf < 2; ++hf) {                                        \
            const ushort* hp = (const ushort*)&vstg[hf * 2];                    \
            const ushort* lp = (const ushort*)&vstg[hf * 2 + 1];                \
            _Pragma("unroll")                                                   \
            for (int i = 0; i < 8; ++i)                                         \
                Vt[NB][vfs * 16 + hf * 8 + i][vrow] =                           \
                    (unsigned)hp[i] | ((unsigned)lp[i] << 16);                  \
        }                                                                       \
    }

    for (int pass = 0; pass < 2; ++pass) {
        const int xq  = pass ? (15 - (int)blockIdx.x) : (int)blockIdx.x;
        const int q0  = xq * 128;
        const int wq0 = q0 + wave * 32;

        // ---- Q fragments (B-operand) into registers: [nf][ks][plane] ----
        short8 qf[2][4][2];
#pragma unroll
        for (int nf = 0; nf < 2; ++nf)
#pragma unroll
            for (int ks = 0; ks < 4; ++ks) {
                size_t base = (((size_t)b * S_ + wq0 + nf * 16 + l15) * NH_ + h) * 256
                            + ks * 32 + quad * 8;
                qf[nf][ks][0] = *(const short8*)&Qsp[base];
                qf[nf][ks][1] = *(const short8*)&Qsp[base + 128];
            }

        f32x4 O[2][8];
#pragma unroll
        for (int mf = 0; mf < 2; ++mf)
#pragma unroll
            for (int nf = 0; nf < 8; ++nf) O[mf][nf] = 0.f;
        float m_[2] = {-3.0e38f, -3.0e38f};
        float l_[2] = {0.f, 0.f};

        const int ntiles = q0 / 32 + 4;

        // ---- prologue: stage tile 0 into buffer 0 ----
        // (previous pass's final barrier guarantees old reads are done)
        LOADKV(0);
        STOREKV(0);
        __syncthreads();

        for (int t = 0; t < ntiles; ++t) {
            const int cur = t & 1;
            const int k0 = t * 32;
            const bool pf = (t + 1 < ntiles);

            // issue tile t+1's global loads NOW — latency hides under compute(t)
            if (pf) LOADKV(k0 + 32);

            // ---- S^T = K . Q^T  (rows kv-permuted, cols q) ----
            f32x4 st[2][2];                    // [nf(q)][mf(kv-tile)]
#pragma unroll
            for (int nf = 0; nf < 2; ++nf)
#pragma unroll
                for (int mf = 0; mf < 2; ++mf) st[nf][mf] = 0.f;
#pragma unroll
            for (int ks = 0; ks < 4; ++ks) {
                short8 kf_h[2], kf_l[2];
#pragma unroll
                for (int mf = 0; mf < 2; ++mf) {
                    kf_h[mf] = *(const short8*)&Ks[cur][mf * 16 + l15][ks * 32 + quad * 8];
                    kf_l[mf] = *(const short8*)&Ks[cur][mf * 16 + l15][144 + ks * 32 + quad * 8];
                }
#pragma unroll
                for (int nf = 0; nf < 2; ++nf)
#pragma unroll
                    for (int mf = 0; mf < 2; ++mf) {
                        st[nf][mf] = __builtin_amdgcn_mfma_f32_16x16x32_bf16(kf_h[mf], qf[nf][ks][0], st[nf][mf], 0, 0, 0);
                        st[nf][mf] = __builtin_amdgcn_mfma_f32_16x16x32_bf16(kf_h[mf], qf[nf][ks][1], st[nf][mf], 0, 0, 0);
                        st[nf][mf] = __builtin_amdgcn_mfma_f32_16x16x32_bf16(kf_l[mf], qf[nf][ks][0], st[nf][mf], 0, 0, 0);
                    }
            }

            // ---- causal mask (actual kv = k0 + quad*8 + mf*4 + r) ----
            if (k0 + 31 > wq0) {
#pragma unroll
                for (int nf = 0; nf < 2; ++nf)
#pragma unroll
                    for (int mf = 0; mf < 2; ++mf)
#pragma unroll
                        for (int r = 0; r < 4; ++r) {
                            int kg = k0 + quad * 8 + mf * 4 + r;
                            int qg = wq0 + nf * 16 + l15;
                            if (kg > qg) st[nf][mf][r] = -3.0e38f;
                        }
            }

            // ---- online softmax (per q column; reduce in-lane + across quads) ----
            float alp[2];
#pragma unroll
            for (int nf = 0; nf < 2; ++nf) {
                float rm = -3.0e38f;
#pragma unroll
                for (int mf = 0; mf < 2; ++mf)
#pragma unroll
                    for (int r = 0; r < 4; ++r) rm = fmaxf(rm, st[nf][mf][r]);
                rm = fmaxf(rm, __shfl_xor(rm, 16));
                rm = fmaxf(rm, __shfl_xor(rm, 32));
                float mn = fmaxf(m_[nf], rm);
                float a  = __expf(m_[nf] - mn);
                float rs = 0.f;
#pragma unroll
                for (int mf = 0; mf < 2; ++mf)
#pragma unroll
                    for (int r = 0; r < 4; ++r) {
                        float p = __expf(st[nf][mf][r] - mn);
                        st[nf][mf][r] = p;
                        rs += p;
                    }
                rs += __shfl_xor(rs, 16);
                rs += __shfl_xor(rs, 32);
                l_[nf] = l_[nf] * a + rs;
                m_[nf] = mn;
                alp[nf] = a;
            }

            // ---- rescale O (alpha fetched from owner lane of each q row) ----
#pragma unroll
            for (int omf = 0; omf < 2; ++omf)
#pragma unroll
                for (int r = 0; r < 4; ++r) {
                    float av = __shfl(alp[omf], (lane & 48) | (quad * 4 + r));
#pragma unroll
                    for (int nf = 0; nf < 8; ++nf) O[omf][nf][r] *= av;
                }

            // ---- P stays in registers: lane already holds kv = quad*8+0..7 ----
            short8 ph[2], pl[2];
#pragma unroll
            for (int omf = 0; omf < 2; ++omf) {
                unsigned hu[4], lu[4];
#pragma unroll
                for (int mf = 0; mf < 2; ++mf)
#pragma unroll
                    for (int pr = 0; pr < 2; ++pr) {
                        unsigned short ah, al, bh, bl;
                        split1(st[omf][mf][pr * 2],     ah, al);
                        split1(st[omf][mf][pr * 2 + 1], bh, bl);
                        hu[mf * 2 + pr] = (unsigned)ah | ((unsigned)bh << 16);
                        lu[mf * 2 + pr] = (unsigned)al | ((unsigned)bl << 16);
                    }
                ph[omf] = *(short8*)hu;
                pl[omf] = *(short8*)lu;
            }

            // ---- O += P . V ----
#pragma unroll
            for (int vnf = 0; vnf < 8; ++vnf) {
                const unsigned* vw = &Vt[cur][vnf * 16 + l15][quad * 8];
                unsigned w[8];
                *(uint4*)w       = *(const uint4*)vw;
                *(uint4*)(w + 4) = *(const uint4*)(vw + 4);
                short8 vh, vl;
                unpack8(w, vh, vl);
#pragma unroll
                for (int omf = 0; omf < 2; ++omf) {
                    O[omf][vnf] = __builtin_amdgcn_mfma_f32_16x16x32_bf16(ph[omf], vh, O[omf][vnf], 0, 0, 0);
                    O[omf][vnf] = __builtin_amdgcn_mfma_f32_16x16x32_bf16(ph[omf], vl, O[omf][vnf], 0, 0, 0);
                    O[omf][vnf] = __builtin_amdgcn_mfma_f32_16x16x32_bf16(pl[omf], vh, O[omf][vnf], 0, 0, 0);
                }
            }

            // ---- write prefetched tile t+1 into the other buffer ----
            if (pf) STOREKV(cur ^ 1);
            __syncthreads();
        }

        // ---- epilogue: normalize, split, store planar ctx ----
        float li[2] = {1.f / l_[0], 1.f / l_[1]};
#pragma unroll
        for (int omf = 0; omf < 2; ++omf)
#pragma unroll
            for (int r = 0; r < 4; ++r) {
                float il = __shfl(li[omf], (lane & 48) | (quad * 4 + r));
                int qrow = wq0 + omf * 16 + quad * 4 + r;
                size_t rowb = ((size_t)b * S_ + qrow) * (size_t)D_ + h * HD_;
#pragma unroll
                for (int nf = 0; nf < 8; ++nf) {
                    float val = O[omf][nf][r] * il;
                    unsigned short hh, ll; split1(val, hh, ll);
                    int feat = nf * 16 + l15;
                    ctx_h[rowb + feat] = hh;
                    ctx_l[rowb + feat] = ll;
                }
            }
    }

#undef LOADKV
#undef STOREKV
}

// ---------------------------------------------------------------------------
extern "C" void kernel_launch(void* const* d_in, const int* in_sizes, int n_in,
                              void* d_out, int out_size, void* d_ws, size_t ws_size,
                              hipStream_t stream)
{
    const float* x    = (const float*)d_in[0];
    const float* wq_w = (const float*)d_in[1];
    const float* wq_b = (const float*)d_in[2];
    const float* wk_w = (const float*)d_in[3];
    const float* wk_b = (const float*)d_in[4];
    const float* wv_w = (const float*)d_in[5];
    const float* wv_b = (const float*)d_in[6];
    const float* wo_w = (const float*)d_in[7];
    float* out = (float*)d_out;

    const int M = B_ * S_;                        // 8192
    const size_t NX   = (size_t)M * D_;           // 16,777,216
    const size_t NKVE = (size_t)M * NKV_ * HD_;   // 4,194,304
    const size_t NWQ  = (size_t)D_ * D_;
    const size_t NWK  = (size_t)(NKV_ * HD_) * D_;

    // workspace layout
    float*  q   = (float*)d_ws;          // becomes interleaved split Q
    float*  k   = q + NX;                // becomes interleaved split K
    float*  v   = k + NKVE;              // becomes interleaved split V
    ushort* xh  = (ushort*)(v + NKVE);   // x hi split; later ctx_h (planar)
    ushort* xl  = xh + NX;               // x lo split; later ctx_l (planar)
    ushort* wqh = xl + NX;
    ushort* wql = wqh + NWQ;
    ushort* wkh = wql + NWQ;
    ushort* wkl = wkh + NWK;
    ushort* wvh = wkl + NWK;
    ushort* wvl = wvh + NWK;
    ushort* woh = wvl + NWK;
    ushort* wol = woh + NWQ;

    // 1) fp32 -> bf16 hi/lo splits
    split_bf16_k<<<NX  / 1024, 256, 0, stream>>>(x,    xh,  xl);
    split_bf16_k<<<NWQ / 1024, 256, 0, stream>>>(wq_w, wqh, wql);
    split_bf16_k<<<NWK / 1024, 256, 0, stream>>>(wk_w, wkh, wkl);
    split_bf16_k<<<NWK / 1024, 256, 0, stream>>>(wv_w, wvh, wvl);
    split_bf16_k<<<NWQ / 1024, 256, 0, stream>>>(wo_w, woh, wol);

    // 2) QKV projections (fp32 outputs)
    gemm_mfma_split<<<dim3(D_/128,         M/128), 256, 0, stream>>>(xh, xl, wqh, wql, wq_b, q, M, D_,       D_);
    gemm_mfma_split<<<dim3((NKV_*HD_)/128, M/128), 256, 0, stream>>>(xh, xl, wkh, wkl, wk_b, k, M, NKV_*HD_, D_);
    gemm_mfma_split<<<dim3((NKV_*HD_)/128, M/128), 256, 0, stream>>>(xh, xl, wvh, wvl, wv_b, v, M, NKV_*HD_, D_);

    // 3) RoPE (+ scale into Q) and in-place interleaved hi/lo split
    rope_split_kernel<<<(M * NH_)  / 2, 256, 0, stream>>>(q, NH_,  0.08838834764831845f, 1);
    rope_split_kernel<<<(M * NKV_) / 2, 256, 0, stream>>>(k, NKV_, 1.0f, 1);
    rope_split_kernel<<<(M * NKV_) / 2, 256, 0, stream>>>(v, NKV_, 1.0f, 0);

    // 4) MFMA flash attention -> planar ctx hi/lo (x splits are dead now)
    //    paired q-tiles: gridDim.x = S/256 = 8, each block does {x, 15-x}
    flash_attn_mfma<<<dim3(S_/256, NH_, B_), 256, 0, stream>>>(
        (const ushort*)q, (const ushort*)k, (const ushort*)v, xh, xl);

    // 5) output projection (round-3-verified planar path)
    gemm_mfma_split<<<dim3(D_/128, M/128), 256, 0, stream>>>(xh, xl, woh, wol, nullptr, out, M, D_, D_);
}

// Round 11
// 1087.887 us; speedup vs baseline: 1.2762x; 1.2762x over previous
//
#include <hip/hip_runtime.h>
#include <cstdint>
#include <cstddef>

#define B_   4
#define S_   2048
#define D_   2048
#define NH_  16
#define NKV_ 4
#define HD_  128

typedef __attribute__((ext_vector_type(8))) short short8;
typedef __attribute__((ext_vector_type(4))) float f32x4;

// ---------------------------------------------------------------------------
// fp32 -> (bf16_hi, bf16_lo) split helpers (RNE)
// ---------------------------------------------------------------------------
__device__ __forceinline__ unsigned short f2bf(float f) {
    union { float f; unsigned u; } v{f};
    unsigned r = v.u + 0x7FFF + ((v.u >> 16) & 1);
    return (unsigned short)(r >> 16);
}
__device__ __forceinline__ float bf2f(unsigned short h) {
    union { unsigned u; float f; } v{(unsigned)h << 16};
    return v.f;
}
__device__ __forceinline__ void split1(float f, unsigned short& h, unsigned short& l) {
    h = f2bf(f);
    l = f2bf(f - bf2f(h));
}
// 8 packed u32 (hi|lo<<16) -> two bf16x8 fragments
__device__ __forceinline__ void unpack8(const unsigned* w, short8& hi, short8& lo) {
    unsigned h[4], l[4];
#pragma unroll
    for (int i = 0; i < 4; ++i) {
        h[i] = (w[2*i] & 0xFFFFu) | (w[2*i+1] << 16);
        l[i] = (w[2*i] >> 16) | (w[2*i+1] & 0xFFFF0000u);
    }
    hi = *(short8*)h; lo = *(short8*)l;
}

// src fp32 [n] -> hi/lo bf16 [n]. n must be a multiple of 1024.
__global__ __launch_bounds__(256) void split_bf16_k(
    const float* __restrict__ src, ushort* __restrict__ hi, ushort* __restrict__ lo)
{
    size_t i = ((size_t)blockIdx.x * 256 + threadIdx.x) * 4;
    float4 f = *(const float4*)&src[i];
    ushort4 h, l;
    split1(f.x, h.x, l.x); split1(f.y, h.y, l.y);
    split1(f.z, h.z, l.z); split1(f.w, h.w, l.w);
    *(ushort4*)&hi[i] = h;
    *(ushort4*)&lo[i] = l;
}

// ---------------------------------------------------------------------------
// Split-bf16 MFMA GEMM (round-3 verified form):
// C[M,N] = (Ah+Al)[M,K] @ (Bh+Bl)[N,K]^T + bias  (drops lo*lo)
// ---------------------------------------------------------------------------
__global__ __launch_bounds__(256) void gemm_mfma_split(
    const ushort* __restrict__ Ah, const ushort* __restrict__ Al,
    const ushort* __restrict__ Bh, const ushort* __restrict__ Bl,
    const float* __restrict__ bias, float* __restrict__ C,
    int M, int N, int K)
{
    __shared__ ushort sA[2][128 * 32];   // [0]=hi [1]=lo, row-major [128][32]
    __shared__ ushort sB[2][128 * 32];

    const int tid  = threadIdx.x;
    const int wave = tid >> 6;
    const int lane = tid & 63;
    const int bm = blockIdx.y * 128;
    const int bn = blockIdx.x * 128;
    const int wm = (wave & 1) * 64;
    const int wn = (wave >> 1) * 64;

    f32x4 acc[4][4];
#pragma unroll
    for (int mt = 0; mt < 4; ++mt)
#pragma unroll
        for (int nt = 0; nt < 4; ++nt) acc[mt][nt] = 0.f;

    const ushort* gbase = (wave == 0) ? Ah : (wave == 1) ? Al : (wave == 2) ? Bh : Bl;
    ushort* sbase = (wave == 0) ? sA[0] : (wave == 1) ? sA[1] : (wave == 2) ? sB[0] : sB[1];
    const int rb   = (wave < 2) ? bm : bn;
    const int lrow = lane >> 2;          // 0..15
    const int lcol = (lane & 3) * 8;     // element offset in k

    const int koff = (lane >> 4) * 8;
    const int rsel = lane & 15;

    for (int k0 = 0; k0 < K; k0 += 32) {
        __syncthreads();
        const ushort* g0 = gbase + (size_t)(rb + lrow) * K + k0 + lcol;
#pragma unroll
        for (int i = 0; i < 8; ++i) {
            __builtin_amdgcn_global_load_lds(
                (const __attribute__((address_space(1))) unsigned int*)(g0 + (size_t)i * 16 * K),
                (__attribute__((address_space(3))) unsigned int*)(sbase + i * 512),
                16, 0, 0);
        }
        __syncthreads();

        short8 a_h[4], a_l[4], b_h[4], b_l[4];
#pragma unroll
        for (int t = 0; t < 4; ++t) {
            a_h[t] = *(const short8*)&sA[0][(wm + t * 16 + rsel) * 32 + koff];
            a_l[t] = *(const short8*)&sA[1][(wm + t * 16 + rsel) * 32 + koff];
            b_h[t] = *(const short8*)&sB[0][(wn + t * 16 + rsel) * 32 + koff];
            b_l[t] = *(const short8*)&sB[1][(wn + t * 16 + rsel) * 32 + koff];
        }
#pragma unroll
        for (int mt = 0; mt < 4; ++mt)
#pragma unroll
            for (int nt = 0; nt < 4; ++nt) {
                acc[mt][nt] = __builtin_amdgcn_mfma_f32_16x16x32_bf16(a_h[mt], b_h[nt], acc[mt][nt], 0, 0, 0);
                acc[mt][nt] = __builtin_amdgcn_mfma_f32_16x16x32_bf16(a_h[mt], b_l[nt], acc[mt][nt], 0, 0, 0);
                acc[mt][nt] = __builtin_amdgcn_mfma_f32_16x16x32_bf16(a_l[mt], b_h[nt], acc[mt][nt], 0, 0, 0);
            }
    }

    const int crow0 = bm + wm + (lane >> 4) * 4;
    const int ccol0 = bn + wn + (lane & 15);
#pragma unroll
    for (int nt = 0; nt < 4; ++nt) {
        float bb = bias ? bias[ccol0 + nt * 16] : 0.f;
#pragma unroll
        for (int mt = 0; mt < 4; ++mt)
#pragma unroll
            for (int r = 0; r < 4; ++r)
                C[(size_t)(crow0 + mt * 16 + r) * N + ccol0 + nt * 16] = acc[mt][nt][r] + bb;
    }
}

// ---------------------------------------------------------------------------
// In-place RoPE (+scale) and fp32 -> interleaved hi/lo bf16 split.
// Row r of 128 fp32 becomes 128 hi ushorts | 128 lo ushorts (same 512 bytes).
// ---------------------------------------------------------------------------
__global__ __launch_bounds__(256) void rope_split_kernel(
    float* __restrict__ t, int H, float scale, int do_rope)
{
    const int tid = threadIdx.x;
    const int rid = blockIdx.x * 2 + (tid >> 7);
    const int d   = tid & 127;
    size_t fbase = (size_t)rid * 128;
    float val;
    if (do_rope) {
        const int s = (rid / H) & (S_ - 1);
        const int j = d & 63;
        float inv  = 1.0f / powf(1.0e6f, (float)j * (1.0f / 64.0f));
        float fr = (float)s * inv;
        float sn, cs; sincosf(fr, &sn, &cs);
        float x0 = t[fbase + d];
        float xp = t[fbase + (d ^ 64)];
        float rot = (d < 64) ? -xp : xp;
        val = fmaf(x0, cs, rot * sn) * scale;
    } else {
        val = t[fbase + d] * scale;
    }
    __syncthreads();               // all fp32 reads of these 2 rows done
    unsigned short h, l; split1(val, h, l);
    ushort* us = (ushort*)t;
    us[(size_t)rid * 256 + d]       = h;
    us[(size_t)rid * 256 + 128 + d] = l;
}

// ---------------------------------------------------------------------------
// MFMA causal flash attention, GQA, split-bf16 precision.
// Qsp: interleaved hi/lo Q rows [B,S,NH]x(128h|128l).
// Ksp/Vsp: interleaved hi/lo K/V rows [B,S,NKV]x(128h|128l).
// ctx_h/ctx_l: PLANAR outputs, [B*S][2048] ushorts, feature = h*128+d.
// Block: 4 waves x 32 q-rows per pass (BM=128); KV tile BN=64 (round 11:
// was 32 — halves barrier count and O-rescale cost per KV element).
//
// Complementary q-tile pairing (R7, verified): block does {x, 15-x}; every
// block does exactly 34 64-KV-tile units; grid 512 = 2 blocks/CU uniform.
//
// K staging (round 11): async global_load_lds, NO register round-trip.
// LDS K layout: Ks[64 rows][256 ushorts] (512B rows, no pad), XOR-swizzled
// at 16B-unit granularity: phys_unit = logical_unit ^ (pr & 7)  — makes the
// 16-lane column reads conflict-free without padding (pad would break the
// contiguous 1KB wave-writes of global_load_lds).
// Row permutation rho64 folded into per-lane SOURCE address: actual kv row
// r stored at pr = [k5 k2 k4 k3 k1 k0]  (inverse r = (pr&32)|((pr&12)<<1)|
// ((pr&16)>>2)|(pr&3)), so the QK^T C-layout leaves lane (l15,quad) holding
// P at kv = (mf>>1)*32 + quad*8 + (mf&1)*4 + r — exactly the two contiguous
// 8-element k-slices the PV A-fragments need. P never touches LDS.
//
// __launch_bounds__(256, 2): allows up to 256 VGPR (R1: (256,4) spills;
// R10: plain (256) also chose a spilling schedule).
// ---------------------------------------------------------------------------
__global__ __launch_bounds__(256, 2) void flash_attn_mfma(
    const ushort* __restrict__ Qsp, const ushort* __restrict__ Ksp,
    const ushort* __restrict__ Vsp, ushort* __restrict__ ctx_h,
    ushort* __restrict__ ctx_l)
{
    __shared__ __align__(16) ushort Ks[64 * 256];     // swizzled, rows = rho64(kv)
    __shared__ __align__(16) unsigned Vt[128][68];    // [feat][kv] hi|lo<<16, 64 kv + pad

    const int tid  = threadIdx.x;
    const int wave = tid >> 6;
    const int lane = tid & 63;
    const int l15  = lane & 15;
    const int quad = lane >> 4;
    const int h    = blockIdx.y;
    const int b    = blockIdx.z;
    const int kvh  = h >> 2;

    const size_t kvstride = (size_t)NKV_ * 256;   // ushorts per kv row (1024)
    const ushort* kbase = Ksp + ((size_t)b * S_ * NKV_ + kvh) * 256;

    // K staging geometry: wave covers pr rows [wave*16, wave*16+16), 8
    // instructions of 1KB. Per-lane source offset (ushorts), tile-invariant:
    int koffl[8];
#pragma unroll
    for (int i = 0; i < 8; ++i) {
        int pr = wave * 16 + i * 2 + (lane >> 5);
        int u  = (lane & 31) ^ (pr & 7);
        int r  = (pr & 32) | ((pr & 12) << 1) | ((pr & 16) >> 2) | (pr & 3);
        koffl[i] = r * 1024 + u * 8;
    }

    // V staging geometry: row = lane (0..63), feat slice = wave*32..+31
    const ushort* vbase = Vsp + ((size_t)b * S_ * NKV_ + kvh) * 256
                        + (size_t)lane * kvstride + wave * 32;

    for (int pass = 0; pass < 2; ++pass) {
        const int xq  = pass ? (15 - (int)blockIdx.x) : (int)blockIdx.x;
        const int q0  = xq * 128;
        const int wq0 = q0 + wave * 32;

        // ---- Q fragments (B-operand) into registers: [nf][ks][plane] ----
        short8 qf[2][4][2];
#pragma unroll
        for (int nf = 0; nf < 2; ++nf)
#pragma unroll
            for (int ks = 0; ks < 4; ++ks) {
                size_t base = (((size_t)b * S_ + wq0 + nf * 16 + l15) * NH_ + h) * 256
                            + ks * 32 + quad * 8;
                qf[nf][ks][0] = *(const short8*)&Qsp[base];
                qf[nf][ks][1] = *(const short8*)&Qsp[base + 128];
            }

        f32x4 O[2][8];
#pragma unroll
        for (int mf = 0; mf < 2; ++mf)
#pragma unroll
            for (int nf = 0; nf < 8; ++nf) O[mf][nf] = 0.f;
        float m_[2] = {-3.0e38f, -3.0e38f};
        float l_[2] = {0.f, 0.f};

        const int ntiles = q0 / 64 + 2;
        for (int t = 0; t < ntiles; ++t) {
            const int k0 = t * 64;
            __syncthreads();               // prev tile's (or pass's) LDS reads done

            // ---- stage K: 8 async 1KB wave-writes, swizzled source ----
            {
                const ushort* ksrc = kbase + (size_t)k0 * kvstride;
                ushort* kdst = Ks + (wave * 16) * 256;
#pragma unroll
                for (int i = 0; i < 8; ++i) {
                    __builtin_amdgcn_global_load_lds(
                        (const __attribute__((address_space(1))) unsigned int*)(ksrc + koffl[i]),
                        (__attribute__((address_space(3))) unsigned int*)(kdst + i * 512),
                        16, 0, 0);
                }
            }
            // ---- stage V transposed+packed: Vt[feat][kv] = hi | lo<<16 ----
            {
                const ushort* src = vbase + (size_t)k0 * kvstride;
#pragma unroll
                for (int hf = 0; hf < 2; ++hf) {
                    uint4 hv0 = *(const uint4*)(src + hf * 16);
                    uint4 hv1 = *(const uint4*)(src + hf * 16 + 8);
                    uint4 lv0 = *(const uint4*)(src + 128 + hf * 16);
                    uint4 lv1 = *(const uint4*)(src + 128 + hf * 16 + 8);
                    const ushort* hp0 = (const ushort*)&hv0;
                    const ushort* hp1 = (const ushort*)&hv1;
                    const ushort* lp0 = (const ushort*)&lv0;
                    const ushort* lp1 = (const ushort*)&lv1;
#pragma unroll
                    for (int i = 0; i < 8; ++i) {
                        Vt[wave * 32 + hf * 16 + i][lane]     = (unsigned)hp0[i] | ((unsigned)lp0[i] << 16);
                        Vt[wave * 32 + hf * 16 + 8 + i][lane] = (unsigned)hp1[i] | ((unsigned)lp1[i] << 16);
                    }
                }
            }
            __syncthreads();

            // ---- S^T = K . Q^T  (rows rho64-permuted, cols q) ----
            f32x4 st[2][4];                // [nf(q)][mf(16-row kv tile)]
#pragma unroll
            for (int nf = 0; nf < 2; ++nf)
#pragma unroll
                for (int mf = 0; mf < 4; ++mf) st[nf][mf] = 0.f;
#pragma unroll
            for (int ks = 0; ks < 4; ++ks) {
                short8 kf_h[4], kf_l[4];
#pragma unroll
                for (int mf = 0; mf < 4; ++mf) {
                    int pr = mf * 16 + l15;
                    int sw = pr & 7;                       // = l15 & 7
                    kf_h[mf] = *(const short8*)&Ks[pr * 256 + (((4 * ks + quad) ^ sw) * 8)];
                    kf_l[mf] = *(const short8*)&Ks[pr * 256 + (((16 + 4 * ks + quad) ^ sw) * 8)];
                }
#pragma unroll
                for (int nf = 0; nf < 2; ++nf)
#pragma unroll
                    for (int mf = 0; mf < 4; ++mf) {
                        st[nf][mf] = __builtin_amdgcn_mfma_f32_16x16x32_bf16(kf_h[mf], qf[nf][ks][0], st[nf][mf], 0, 0, 0);
                        st[nf][mf] = __builtin_amdgcn_mfma_f32_16x16x32_bf16(kf_h[mf], qf[nf][ks][1], st[nf][mf], 0, 0, 0);
                        st[nf][mf] = __builtin_amdgcn_mfma_f32_16x16x32_bf16(kf_l[mf], qf[nf][ks][0], st[nf][mf], 0, 0, 0);
                    }
            }

            // ---- causal mask (kv = k0 + (mf>>1)*32 + quad*8 + (mf&1)*4 + r) ----
            if (k0 + 63 > wq0) {
#pragma unroll
                for (int nf = 0; nf < 2; ++nf)
#pragma unroll
                    for (int mf = 0; mf < 4; ++mf)
#pragma unroll
                        for (int r = 0; r < 4; ++r) {
                            int kg = k0 + ((mf & 2) << 4) + quad * 8 + ((mf & 1) << 2) + r;
                            int qg = wq0 + nf * 16 + l15;
                            if (kg > qg) st[nf][mf][r] = -3.0e38f;
                        }
            }

            // ---- online softmax (per q column; reduce in-lane + across quads) ----
            float alp[2];
#pragma unroll
            for (int nf = 0; nf < 2; ++nf) {
                float rm = -3.0e38f;
#pragma unroll
                for (int mf = 0; mf < 4; ++mf)
#pragma unroll
                    for (int r = 0; r < 4; ++r) rm = fmaxf(rm, st[nf][mf][r]);
                rm = fmaxf(rm, __shfl_xor(rm, 16));
                rm = fmaxf(rm, __shfl_xor(rm, 32));
                float mn = fmaxf(m_[nf], rm);
                float a  = __expf(m_[nf] - mn);
                float rs = 0.f;
#pragma unroll
                for (int mf = 0; mf < 4; ++mf)
#pragma unroll
                    for (int r = 0; r < 4; ++r) {
                        float p = __expf(st[nf][mf][r] - mn);
                        st[nf][mf][r] = p;
                        rs += p;
                    }
                rs += __shfl_xor(rs, 16);
                rs += __shfl_xor(rs, 32);
                l_[nf] = l_[nf] * a + rs;
                m_[nf] = mn;
                alp[nf] = a;
            }

            // ---- rescale O (alpha fetched from owner lane of each q row) ----
#pragma unroll
            for (int omf = 0; omf < 2; ++omf)
#pragma unroll
                for (int r = 0; r < 4; ++r) {
                    float av = __shfl(alp[omf], (lane & 48) | (quad * 4 + r));
#pragma unroll
                    for (int nf = 0; nf < 8; ++nf) O[omf][nf][r] *= av;
                }

            // ---- P in registers: lane holds kv chunks c*32 + quad*8 + 0..7 ----
            short8 ph[2][2], pl[2][2];     // [omf][chunk]
#pragma unroll
            for (int omf = 0; omf < 2; ++omf)
#pragma unroll
                for (int c = 0; c < 2; ++c) {
                    unsigned hu[4], lu[4];
#pragma unroll
                    for (int mf_ = 0; mf_ < 2; ++mf_)
#pragma unroll
                        for (int pr_ = 0; pr_ < 2; ++pr_) {
                            unsigned short ah, al, bh, bl;
                            split1(st[omf][c * 2 + mf_][pr_ * 2],     ah, al);
                            split1(st[omf][c * 2 + mf_][pr_ * 2 + 1], bh, bl);
                            hu[mf_ * 2 + pr_] = (unsigned)ah | ((unsigned)bh << 16);
                            lu[mf_ * 2 + pr_] = (unsigned)al | ((unsigned)bl << 16);
                        }
                    ph[omf][c] = *(short8*)hu;
                    pl[omf][c] = *(short8*)lu;
                }

            // ---- O += P . V  (two K=32 chunks) ----
#pragma unroll
            for (int c = 0; c < 2; ++c)
#pragma unroll
                for (int vnf = 0; vnf < 8; ++vnf) {
                    const unsigned* vw = &Vt[vnf * 16 + l15][c * 32 + quad * 8];
                    unsigned w[8];
                    *(uint4*)w       = *(const uint4*)vw;
                    *(uint4*)(w + 4) = *(const uint4*)(vw + 4);
                    short8 vh, vl;
                    unpack8(w, vh, vl);
#pragma unroll
                    for (int omf = 0; omf < 2; ++omf) {
                        O[omf][vnf] = __builtin_amdgcn_mfma_f32_16x16x32_bf16(ph[omf][c], vh, O[omf][vnf], 0, 0, 0);
                        O[omf][vnf] = __builtin_amdgcn_mfma_f32_16x16x32_bf16(ph[omf][c], vl, O[omf][vnf], 0, 0, 0);
                        O[omf][vnf] = __builtin_amdgcn_mfma_f32_16x16x32_bf16(pl[omf][c], vh, O[omf][vnf], 0, 0, 0);
                    }
                }
        }

        // ---- epilogue: normalize, split, store planar ctx ----
        float li[2] = {1.f / l_[0], 1.f / l_[1]};
#pragma unroll
        for (int omf = 0; omf < 2; ++omf)
#pragma unroll
            for (int r = 0; r < 4; ++r) {
                float il = __shfl(li[omf], (lane & 48) | (quad * 4 + r));
                int qrow = wq0 + omf * 16 + quad * 4 + r;
                size_t rowb = ((size_t)b * S_ + qrow) * (size_t)D_ + h * HD_;
#pragma unroll
                for (int nf = 0; nf < 8; ++nf) {
                    float val = O[omf][nf][r] * il;
                    unsigned short hh, ll; split1(val, hh, ll);
                    int feat = nf * 16 + l15;
                    ctx_h[rowb + feat] = hh;
                    ctx_l[rowb + feat] = ll;
                }
            }
    }
}

// ---------------------------------------------------------------------------
extern "C" void kernel_launch(void* const* d_in, const int* in_sizes, int n_in,
                              void* d_out, int out_size, void* d_ws, size_t ws_size,
                              hipStream_t stream)
{
    const float* x    = (const float*)d_in[0];
    const float* wq_w = (const float*)d_in[1];
    const float* wq_b = (const float*)d_in[2];
    const float* wk_w = (const float*)d_in[3];
    const float* wk_b = (const float*)d_in[4];
    const float* wv_w = (const float*)d_in[5];
    const float* wv_b = (const float*)d_in[6];
    const float* wo_w = (const float*)d_in[7];
    float* out = (float*)d_out;

    const int M = B_ * S_;                        // 8192
    const size_t NX   = (size_t)M * D_;           // 16,777,216
    const size_t NKVE = (size_t)M * NKV_ * HD_;   // 4,194,304
    const size_t NWQ  = (size_t)D_ * D_;
    const size_t NWK  = (size_t)(NKV_ * HD_) * D_;

    // workspace layout
    float*  q   = (float*)d_ws;          // becomes interleaved split Q
    float*  k   = q + NX;                // becomes interleaved split K
    float*  v   = k + NKVE;              // becomes interleaved split V
    ushort* xh  = (ushort*)(v + NKVE);   // x hi split; later ctx_h (planar)
    ushort* xl  = xh + NX;               // x lo split; later ctx_l (planar)
    ushort* wqh = xl + NX;
    ushort* wql = wqh + NWQ;
    ushort* wkh = wql + NWQ;
    ushort* wkl = wkh + NWK;
    ushort* wvh = wkl + NWK;
    ushort* wvl = wvh + NWK;
    ushort* woh = wvl + NWK;
    ushort* wol = woh + NWQ;

    // 1) fp32 -> bf16 hi/lo splits
    split_bf16_k<<<NX  / 1024, 256, 0, stream>>>(x,    xh,  xl);
    split_bf16_k<<<NWQ / 1024, 256, 0, stream>>>(wq_w, wqh, wql);
    split_bf16_k<<<NWK / 1024, 256, 0, stream>>>(wk_w, wkh, wkl);
    split_bf16_k<<<NWK / 1024, 256, 0, stream>>>(wv_w, wvh, wvl);
    split_bf16_k<<<NWQ / 1024, 256, 0, stream>>>(wo_w, woh, wol);

    // 2) QKV projections (fp32 outputs)
    gemm_mfma_split<<<dim3(D_/128,         M/128), 256, 0, stream>>>(xh, xl, wqh, wql, wq_b, q, M, D_,       D_);
    gemm_mfma_split<<<dim3((NKV_*HD_)/128, M/128), 256, 0, stream>>>(xh, xl, wkh, wkl, wk_b, k, M, NKV_*HD_, D_);
    gemm_mfma_split<<<dim3((NKV_*HD_)/128, M/128), 256, 0, stream>>>(xh, xl, wvh, wvl, wv_b, v, M, NKV_*HD_, D_);

    // 3) RoPE (+ scale into Q) and in-place interleaved hi/lo split
    rope_split_kernel<<<(M * NH_)  / 2, 256, 0, stream>>>(q, NH_,  0.08838834764831845f, 1);
    rope_split_kernel<<<(M * NKV_) / 2, 256, 0, stream>>>(k, NKV_, 1.0f, 1);
    rope_split_kernel<<<(M * NKV_) / 2, 256, 0, stream>>>(v, NKV_, 1.0f, 0);

    // 4) MFMA flash attention -> planar ctx hi/lo (x splits are dead now)
    //    paired q-tiles: gridDim.x = S/256 = 8, each block does {x, 15-x}
    flash_attn_mfma<<<dim3(S_/256, NH_, B_), 256, 0, stream>>>(
        (const ushort*)q, (const ushort*)k, (const ushort*)v, xh, xl);

    // 5) output projection (round-3-verified planar path)
    gemm_mfma_split<<<dim3(D_/128, M/128), 256, 0, stream>>>(xh, xl, woh, wol, nullptr, out, M, D_, D_);
}